// Round 1
// baseline (620.987 us; speedup 1.0000x reference)
//
#include <hip/hip_runtime.h>
#include <hip/hip_bf16.h>

#define XDIM 14087   // 4*3481 conv + 162 atm + 1 egfn1
#define NATM 81
#define BS   128

__device__ __forceinline__ float silu(float z) {
    return z / (1.f + __expf(-z));
}
__device__ __forceinline__ float leaky(float z) {
    return (z > 0.f) ? z : 0.01f * z;
}

// ---------------------------------------------------------------------------
// EGNN: one block per (r,b). 486 active threads = 81 i-nodes x 3 j-parts x 2 k2-halves.
// Writes atm (cols 13924..14085) and egfn1 (col 14086) of xbuf row.
// ---------------------------------------------------------------------------
__global__ __launch_bounds__(512) void egnn_kernel(
    const float* __restrict__ xyz, const float* __restrict__ cn,
    const float* __restrict__ edisp, const float* __restrict__ egfn1,
    const float* __restrict__ We1, const float* __restrict__ be1,
    const float* __restrict__ We2, const float* __restrict__ be2,
    const float* __restrict__ Wn1, const float* __restrict__ bn1,
    const float* __restrict__ Wn2, const float* __restrict__ bn2,
    float* __restrict__ xbuf)
{
    const int bid = blockIdx.x;      // r*128 + b
    const int tid = threadIdx.x;

    __shared__ float sc[NATM][3];
    __shared__ float sf[NATM][2];
    __shared__ float sai[NATM][10];
    __shared__ float sbj[NATM][10];
    __shared__ float sW2[160];
    __shared__ float sbe2[16];
    __shared__ float sw5[10];
    __shared__ float sWn1[72];
    __shared__ float sbn1[4];
    __shared__ float sWn2[8];
    __shared__ float sbn2[2];
    __shared__ float smp[3][NATM][17];   // padded stride 17 to break bank conflicts

    const float* xb = xyz + (size_t)bid * NATM * 3;
    for (int idx = tid; idx < NATM * 3; idx += 512) sc[idx / 3][idx % 3] = xb[idx];
    if (tid < NATM) {
        const float f0 = cn[(size_t)bid * NATM + tid];
        const float f1 = edisp[(size_t)bid * NATM + tid];
        sf[tid][0] = f0; sf[tid][1] = f1;
        #pragma unroll
        for (int k = 0; k < 10; ++k) {
            sai[tid][k] = be1[k] + We1[k * 5 + 0] * f0 + We1[k * 5 + 1] * f1;
            sbj[tid][k] =          We1[k * 5 + 2] * f0 + We1[k * 5 + 3] * f1;
        }
    }
    if (tid < 160) sW2[tid] = We2[tid];
    if (tid < 16)  sbe2[tid] = be2[tid];
    if (tid < 10)  sw5[tid] = We1[tid * 5 + 4];
    if (tid < 72)  sWn1[tid] = Wn1[tid];
    if (tid < 4)   sbn1[tid] = bn1[tid];
    if (tid < 8)   sWn2[tid] = Wn2[tid];
    if (tid < 2)   sbn2[tid] = bn2[tid];
    __syncthreads();

    if (tid < 486) {
        const int i    = tid % 81;
        const int part = (tid / 81) % 3;
        const int half = tid / 243;      // 0 or 1: which 8 of the 16 m-channels

        float W2r[80];
        #pragma unroll
        for (int q = 0; q < 80; ++q) W2r[q] = sW2[half * 80 + q];
        float be2r[8];
        #pragma unroll
        for (int q = 0; q < 8; ++q) be2r[q] = sbe2[half * 8 + q];
        float w5r[10];
        #pragma unroll
        for (int k = 0; k < 10; ++k) w5r[k] = sw5[k];
        float air[10];
        #pragma unroll
        for (int k = 0; k < 10; ++k) air[k] = sai[i][k];
        const float ci0 = sc[i][0], ci1 = sc[i][1], ci2 = sc[i][2];

        float macc[8];
        #pragma unroll
        for (int q = 0; q < 8; ++q) macc[q] = 0.f;

        const int j0 = part * 27;
        for (int j = j0; j < j0 + 27; ++j) {
            const float dx = ci0 - sc[j][0];
            const float dy = ci1 - sc[j][1];
            const float dz = ci2 - sc[j][2];
            const float rd = dx * dx + dy * dy + dz * dz;
            float h[10];
            #pragma unroll
            for (int k = 0; k < 10; ++k) {
                const float z = air[k] + sbj[j][k] + w5r[k] * rd;
                h[k] = silu(z);
            }
            #pragma unroll
            for (int q = 0; q < 8; ++q) {
                float z = be2r[q];
                #pragma unroll
                for (int k = 0; k < 10; ++k) z += W2r[q * 10 + k] * h[k];
                macc[q] += silu(z);
            }
        }
        #pragma unroll
        for (int q = 0; q < 8; ++q) smp[part][i][half * 8 + q] = macc[q];
    }
    __syncthreads();

    if (tid < NATM) {
        float mi[16];
        #pragma unroll
        for (int q = 0; q < 16; ++q)
            mi[q] = smp[0][tid][q] + smp[1][tid][q] + smp[2][tid][q];
        const float f0 = sf[tid][0], f1 = sf[tid][1];
        float n1[4];
        #pragma unroll
        for (int k = 0; k < 4; ++k) {
            float z = sbn1[k] + sWn1[k * 18 + 0] * f0 + sWn1[k * 18 + 1] * f1;
            #pragma unroll
            for (int q = 0; q < 16; ++q) z += sWn1[k * 18 + 2 + q] * mi[q];
            n1[k] = silu(z);
        }
        float* xrow = xbuf + (size_t)bid * XDIM + 13924 + tid * 2;
        #pragma unroll
        for (int c = 0; c < 2; ++c) {
            float z = sbn2[c] + (c ? f1 : f0);
            #pragma unroll
            for (int k = 0; k < 4; ++k) z += sWn2[c * 4 + k] * n1[k];
            xrow[c] = z;
        }
    }
    if (tid == 0) xbuf[(size_t)bid * XDIM + 14086] = egfn1[bid];
}

// ---------------------------------------------------------------------------
// Fused conv1(2x2)+leaky+pool2 + conv2(2x2)+leaky+pool2 for one image strip.
// Block = one (tensor, r, b, strip-of-4-output-rows). Final out (2,59,59).
// Each final pixel (y,x) depends on input rows 4y..4y+6, cols 4x..4x+6.
// ---------------------------------------------------------------------------
__global__ __launch_bounds__(256) void conv_kernel(
    const float* __restrict__ ovlp, const float* __restrict__ h0,
    const float* __restrict__ w1, const float* __restrict__ b1,
    const float* __restrict__ w2, const float* __restrict__ b2,
    float* __restrict__ xbuf)
{
    const int bid   = blockIdx.x;
    const int strip = bid % 15;          // 15 strips x 4 rows = 60 >= 59
    const int img   = bid / 15;          // r*256 + t*128 + b
    const int b     = img % 128;
    const int t     = (img / 128) % 2;
    const int r     = img / 256;
    const int tid   = threadIdx.x;

    const float* src = (t ? h0 : ovlp) + (size_t)(r * BS + b) * 57600;

    __shared__ __align__(16) float T[19][240];
    const int gy0 = strip * 16;
    for (int idx = tid; idx < 19 * 240; idx += 256) {
        const int lr = idx / 240, lc = idx % 240;
        const int gy = gy0 + lr;
        T[lr][lc] = (gy < 240) ? src[gy * 240 + lc] : 0.f;
    }

    float w1r[8], w2r[16], b1r[2], b2r[2];
    #pragma unroll
    for (int k = 0; k < 8; ++k) w1r[k] = w1[k];
    #pragma unroll
    for (int k = 0; k < 16; ++k) w2r[k] = w2[k];
    b1r[0] = b1[0]; b1r[1] = b1[1];
    b2r[0] = b2[0]; b2r[1] = b2[1];
    __syncthreads();

    const int wv = tid >> 6;             // wave -> output row within strip
    const int l  = tid & 63;             // lane -> output col
    const int y  = strip * 4 + wv;
    const int x  = l;
    const bool valid = (x < 59) && (y < 59);
    const int  xc = (x < 59) ? x : 0;    // clamp so idle lanes read in-bounds

    // 7x8 input patch into registers via two b128 LDS reads per row
    float P[7][8];
    #pragma unroll
    for (int rr = 0; rr < 7; ++rr) {
        const float4 a  = *reinterpret_cast<const float4*>(&T[4 * wv + rr][4 * xc]);
        const float4 bq = *reinterpret_cast<const float4*>(&T[4 * wv + rr][4 * xc + 4]);
        P[rr][0] = a.x;  P[rr][1] = a.y;  P[rr][2] = a.z;  P[rr][3] = a.w;
        P[rr][4] = bq.x; P[rr][5] = bq.y; P[rr][6] = bq.z; P[rr][7] = bq.w;
    }

    // conv1 + leaky + pool2 -> p1[2][3][3]
    float p1[2][3][3];
    #pragma unroll
    for (int c = 0; c < 2; ++c) {
        const float wa = w1r[c * 4 + 0], wb = w1r[c * 4 + 1];
        const float wc = w1r[c * 4 + 2], wd = w1r[c * 4 + 3];
        const float bb = b1r[c];
        #pragma unroll
        for (int pp = 0; pp < 3; ++pp)
        #pragma unroll
        for (int qq = 0; qq < 3; ++qq) {
            float mx = -3.4e38f;
            #pragma unroll
            for (int s = 0; s < 2; ++s)
            #pragma unroll
            for (int tt = 0; tt < 2; ++tt) {
                const int u = 2 * pp + s, v = 2 * qq + tt;
                float a = fmaf(wa, P[u][v], fmaf(wb, P[u][v + 1],
                          fmaf(wc, P[u + 1][v], fmaf(wd, P[u + 1][v + 1], bb))));
                a = leaky(a);
                mx = fmaxf(mx, a);
            }
            p1[c][pp][qq] = mx;
        }
    }

    // conv2 + leaky + pool2 -> 2 outputs
    if (valid) {
        float* xrow = xbuf + (size_t)(r * BS + b) * XDIM + (size_t)(t * 2) * 3481
                      + y * 59 + x;
        #pragma unroll
        for (int c2 = 0; c2 < 2; ++c2) {
            float mx = -3.4e38f;
            #pragma unroll
            for (int a2 = 0; a2 < 2; ++a2)
            #pragma unroll
            for (int b2i = 0; b2i < 2; ++b2i) {
                float acc = b2r[c2];
                #pragma unroll
                for (int c1 = 0; c1 < 2; ++c1)
                #pragma unroll
                for (int du = 0; du < 2; ++du)
                #pragma unroll
                for (int dv = 0; dv < 2; ++dv)
                    acc += w2r[((c2 * 2 + c1) * 2 + du) * 2 + dv]
                         * p1[c1][a2 + du][b2i + dv];
                mx = fmaxf(mx, leaky(acc));
            }
            xrow[(size_t)c2 * 3481] = mx;
        }
    }
}

// ---------------------------------------------------------------------------
// FC head: one block per (r,b). x-row in LDS; wave per fc1 output row.
// ---------------------------------------------------------------------------
__global__ __launch_bounds__(256) void fc_kernel(
    const float* __restrict__ xbuf,
    const float* __restrict__ fc1w, const float* __restrict__ fc1b,
    const float* __restrict__ fc2w, const float* __restrict__ fc2b,
    const float* __restrict__ fc3w, const float* __restrict__ fc3b,
    const float* __restrict__ nu, float* __restrict__ out)
{
    const int bid = blockIdx.x;   // r*128 + b
    const int r = bid >> 7, b = bid & 127;
    const int tid = threadIdx.x;

    __shared__ float xs[XDIM];
    __shared__ float y1[60];
    __shared__ float y2[30];

    const float* xrow = xbuf + (size_t)bid * XDIM;
    for (int idx = tid; idx < XDIM; idx += 256) xs[idx] = xrow[idx];
    __syncthreads();

    const int wv = tid >> 6, l = tid & 63;
    for (int o = wv; o < 60; o += 4) {
        const float* wr = fc1w + (size_t)o * XDIM;
        float acc = 0.f;
        int f = l;
        #pragma unroll 4
        for (; f < 14080; f += 64) acc += xs[f] * wr[f];   // 220 full strides
        if (f < XDIM) acc += xs[f] * wr[f];                // 7-element tail
        #pragma unroll
        for (int off = 32; off > 0; off >>= 1) acc += __shfl_down(acc, off);
        if (l == 0) y1[o] = leaky(acc + fc1b[o]);
    }
    __syncthreads();

    if (tid < 30) {
        float acc = fc2b[tid];
        const float* wr = fc2w + tid * 60;
        #pragma unroll
        for (int k = 0; k < 60; ++k) acc += wr[k] * y1[k];
        y2[tid] = leaky(acc);
    }
    __syncthreads();

    if (tid == 0) {
        float acc = fc3b[0];
        #pragma unroll
        for (int k = 0; k < 30; ++k) acc += fc3w[k] * y2[k];
        atomicAdd(&out[b], acc * nu[b * 2 + r]);   // nu shape (BS, R)
    }
}

__global__ void zero_out_kernel(float* __restrict__ out, int n) {
    const int i = blockIdx.x * blockDim.x + threadIdx.x;
    if (i < n) out[i] = 0.f;
}

extern "C" void kernel_launch(void* const* d_in, const int* in_sizes, int n_in,
                              void* d_out, int out_size, void* d_ws, size_t ws_size,
                              hipStream_t stream)
{
    const float* xyz   = (const float*)d_in[0];
    const float* cn    = (const float*)d_in[1];
    const float* edisp = (const float*)d_in[2];
    const float* ovlp  = (const float*)d_in[3];
    const float* h0    = (const float*)d_in[4];
    const float* egfn1 = (const float*)d_in[5];
    const float* nu    = (const float*)d_in[6];
    const float* We1   = (const float*)d_in[7];
    const float* be1   = (const float*)d_in[8];
    const float* We2   = (const float*)d_in[9];
    const float* be2   = (const float*)d_in[10];
    // d_in[11..15] = Wc1,bc1,Wc2,bc2,coors_scale: dead code (coors_out discarded)
    const float* Wn1   = (const float*)d_in[16];
    const float* bn1   = (const float*)d_in[17];
    const float* Wn2   = (const float*)d_in[18];
    const float* bn2   = (const float*)d_in[19];
    const float* c1w   = (const float*)d_in[20];
    const float* c1b   = (const float*)d_in[21];
    const float* c2w   = (const float*)d_in[22];
    const float* c2b   = (const float*)d_in[23];
    const float* fc1w  = (const float*)d_in[24];
    const float* fc1b  = (const float*)d_in[25];
    const float* fc2w  = (const float*)d_in[26];
    const float* fc2b  = (const float*)d_in[27];
    const float* fc3w  = (const float*)d_in[28];
    const float* fc3b  = (const float*)d_in[29];

    float* xbuf = (float*)d_ws;          // (2*128, 14087) f32 = 14.4 MB
    float* out  = (float*)d_out;

    hipLaunchKernelGGL(egnn_kernel, dim3(256), dim3(512), 0, stream,
                       xyz, cn, edisp, egfn1, We1, be1, We2, be2,
                       Wn1, bn1, Wn2, bn2, xbuf);
    hipLaunchKernelGGL(conv_kernel, dim3(2 * 2 * BS * 15), dim3(256), 0, stream,
                       ovlp, h0, c1w, c1b, c2w, c2b, xbuf);
    hipLaunchKernelGGL(zero_out_kernel, dim3(1), dim3(256), 0, stream, out, out_size);
    hipLaunchKernelGGL(fc_kernel, dim3(256), dim3(256), 0, stream,
                       xbuf, fc1w, fc1b, fc2w, fc2b, fc3w, fc3b, nu, out);
}

// Round 2
// 309.643 us; speedup vs baseline: 2.0055x; 2.0055x over previous
//
#include <hip/hip_runtime.h>
#include <hip/hip_bf16.h>

#define XDIM 14087   // 4*3481 conv + 162 atm + 1 egfn1
#define NATM 81
#define BS   128
#define KC   128          // K-chunk for fc1 GEMM
#define NKCH 111          // ceil(14087/128)

__device__ __forceinline__ float silu(float z) {
    return z / (1.f + __expf(-z));
}
__device__ __forceinline__ float leaky(float z) {
    return (z > 0.f) ? z : 0.01f * z;
}

// ---------------------------------------------------------------------------
// EGNN: one block per (r,b). 486 active threads = 81 i-nodes x 3 j-parts x 2 k2-halves.
// Writes atm (cols 13924..14085) and egfn1 (col 14086) of xbuf row.
// ---------------------------------------------------------------------------
__global__ __launch_bounds__(512) void egnn_kernel(
    const float* __restrict__ xyz, const float* __restrict__ cn,
    const float* __restrict__ edisp, const float* __restrict__ egfn1,
    const float* __restrict__ We1, const float* __restrict__ be1,
    const float* __restrict__ We2, const float* __restrict__ be2,
    const float* __restrict__ Wn1, const float* __restrict__ bn1,
    const float* __restrict__ Wn2, const float* __restrict__ bn2,
    float* __restrict__ xbuf)
{
    const int bid = blockIdx.x;      // r*128 + b
    const int tid = threadIdx.x;

    __shared__ float sc[NATM][3];
    __shared__ float sf[NATM][2];
    __shared__ float sai[NATM][10];
    __shared__ float sbj[NATM][10];
    __shared__ float sW2[160];
    __shared__ float sbe2[16];
    __shared__ float sw5[10];
    __shared__ float sWn1[72];
    __shared__ float sbn1[4];
    __shared__ float sWn2[8];
    __shared__ float sbn2[2];
    __shared__ float smp[3][NATM][17];   // padded stride 17 to break bank conflicts

    const float* xb = xyz + (size_t)bid * NATM * 3;
    for (int idx = tid; idx < NATM * 3; idx += 512) sc[idx / 3][idx % 3] = xb[idx];
    if (tid < NATM) {
        const float f0 = cn[(size_t)bid * NATM + tid];
        const float f1 = edisp[(size_t)bid * NATM + tid];
        sf[tid][0] = f0; sf[tid][1] = f1;
        #pragma unroll
        for (int k = 0; k < 10; ++k) {
            sai[tid][k] = be1[k] + We1[k * 5 + 0] * f0 + We1[k * 5 + 1] * f1;
            sbj[tid][k] =          We1[k * 5 + 2] * f0 + We1[k * 5 + 3] * f1;
        }
    }
    if (tid < 160) sW2[tid] = We2[tid];
    if (tid < 16)  sbe2[tid] = be2[tid];
    if (tid < 10)  sw5[tid] = We1[tid * 5 + 4];
    if (tid < 72)  sWn1[tid] = Wn1[tid];
    if (tid < 4)   sbn1[tid] = bn1[tid];
    if (tid < 8)   sWn2[tid] = Wn2[tid];
    if (tid < 2)   sbn2[tid] = bn2[tid];
    __syncthreads();

    if (tid < 486) {
        const int i    = tid % 81;
        const int part = (tid / 81) % 3;
        const int half = tid / 243;      // 0 or 1: which 8 of the 16 m-channels

        float W2r[80];
        #pragma unroll
        for (int q = 0; q < 80; ++q) W2r[q] = sW2[half * 80 + q];
        float be2r[8];
        #pragma unroll
        for (int q = 0; q < 8; ++q) be2r[q] = sbe2[half * 8 + q];
        float w5r[10];
        #pragma unroll
        for (int k = 0; k < 10; ++k) w5r[k] = sw5[k];
        float air[10];
        #pragma unroll
        for (int k = 0; k < 10; ++k) air[k] = sai[i][k];
        const float ci0 = sc[i][0], ci1 = sc[i][1], ci2 = sc[i][2];

        float macc[8];
        #pragma unroll
        for (int q = 0; q < 8; ++q) macc[q] = 0.f;

        const int j0 = part * 27;
        for (int j = j0; j < j0 + 27; ++j) {
            const float dx = ci0 - sc[j][0];
            const float dy = ci1 - sc[j][1];
            const float dz = ci2 - sc[j][2];
            const float rd = dx * dx + dy * dy + dz * dz;
            float h[10];
            #pragma unroll
            for (int k = 0; k < 10; ++k) {
                const float z = air[k] + sbj[j][k] + w5r[k] * rd;
                h[k] = silu(z);
            }
            #pragma unroll
            for (int q = 0; q < 8; ++q) {
                float z = be2r[q];
                #pragma unroll
                for (int k = 0; k < 10; ++k) z += W2r[q * 10 + k] * h[k];
                macc[q] += silu(z);
            }
        }
        #pragma unroll
        for (int q = 0; q < 8; ++q) smp[part][i][half * 8 + q] = macc[q];
    }
    __syncthreads();

    if (tid < NATM) {
        float mi[16];
        #pragma unroll
        for (int q = 0; q < 16; ++q)
            mi[q] = smp[0][tid][q] + smp[1][tid][q] + smp[2][tid][q];
        const float f0 = sf[tid][0], f1 = sf[tid][1];
        float n1[4];
        #pragma unroll
        for (int k = 0; k < 4; ++k) {
            float z = sbn1[k] + sWn1[k * 18 + 0] * f0 + sWn1[k * 18 + 1] * f1;
            #pragma unroll
            for (int q = 0; q < 16; ++q) z += sWn1[k * 18 + 2 + q] * mi[q];
            n1[k] = silu(z);
        }
        float* xrow = xbuf + (size_t)bid * XDIM + 13924 + tid * 2;
        #pragma unroll
        for (int c = 0; c < 2; ++c) {
            float z = sbn2[c] + (c ? f1 : f0);
            #pragma unroll
            for (int k = 0; k < 4; ++k) z += sWn2[c * 4 + k] * n1[k];
            xrow[c] = z;
        }
    }
    if (tid == 0) xbuf[(size_t)bid * XDIM + 14086] = egfn1[bid];
}

// ---------------------------------------------------------------------------
// Fused conv1(2x2)+leaky+pool2 + conv2(2x2)+leaky+pool2 for one image strip.
// ---------------------------------------------------------------------------
__global__ __launch_bounds__(256) void conv_kernel(
    const float* __restrict__ ovlp, const float* __restrict__ h0,
    const float* __restrict__ w1, const float* __restrict__ b1,
    const float* __restrict__ w2, const float* __restrict__ b2,
    float* __restrict__ xbuf)
{
    const int bid   = blockIdx.x;
    const int strip = bid % 15;          // 15 strips x 4 rows = 60 >= 59
    const int img   = bid / 15;          // r*256 + t*128 + b
    const int b     = img % 128;
    const int t     = (img / 128) % 2;
    const int r     = img / 256;
    const int tid   = threadIdx.x;

    const float* src = (t ? h0 : ovlp) + (size_t)(r * BS + b) * 57600;
    const float4* src4 = reinterpret_cast<const float4*>(src);

    __shared__ __align__(16) float T[19][240];
    const int gy0 = strip * 16;
    const float4 zero4 = make_float4(0.f, 0.f, 0.f, 0.f);
    for (int idx = tid; idx < 19 * 60; idx += 256) {
        const int lr = idx / 60, c4 = idx % 60;
        const int gy = gy0 + lr;
        reinterpret_cast<float4*>(&T[lr][0])[c4] =
            (gy < 240) ? src4[gy * 60 + c4] : zero4;
    }

    float w1r[8], w2r[16], b1r[2], b2r[2];
    #pragma unroll
    for (int k = 0; k < 8; ++k) w1r[k] = w1[k];
    #pragma unroll
    for (int k = 0; k < 16; ++k) w2r[k] = w2[k];
    b1r[0] = b1[0]; b1r[1] = b1[1];
    b2r[0] = b2[0]; b2r[1] = b2[1];
    __syncthreads();

    const int wv = tid >> 6;             // wave -> output row within strip
    const int l  = tid & 63;             // lane -> output col
    const int y  = strip * 4 + wv;
    const int x  = l;
    const bool valid = (x < 59) && (y < 59);
    const int  xc = (x < 59) ? x : 0;    // clamp so idle lanes read in-bounds

    float P[7][8];
    #pragma unroll
    for (int rr = 0; rr < 7; ++rr) {
        const float4 a  = *reinterpret_cast<const float4*>(&T[4 * wv + rr][4 * xc]);
        const float4 bq = *reinterpret_cast<const float4*>(&T[4 * wv + rr][4 * xc + 4]);
        P[rr][0] = a.x;  P[rr][1] = a.y;  P[rr][2] = a.z;  P[rr][3] = a.w;
        P[rr][4] = bq.x; P[rr][5] = bq.y; P[rr][6] = bq.z; P[rr][7] = bq.w;
    }

    float p1[2][3][3];
    #pragma unroll
    for (int c = 0; c < 2; ++c) {
        const float wa = w1r[c * 4 + 0], wb = w1r[c * 4 + 1];
        const float wc = w1r[c * 4 + 2], wd = w1r[c * 4 + 3];
        const float bb = b1r[c];
        #pragma unroll
        for (int pp = 0; pp < 3; ++pp)
        #pragma unroll
        for (int qq = 0; qq < 3; ++qq) {
            float mx = -3.4e38f;
            #pragma unroll
            for (int s = 0; s < 2; ++s)
            #pragma unroll
            for (int tt = 0; tt < 2; ++tt) {
                const int u = 2 * pp + s, v = 2 * qq + tt;
                float a = fmaf(wa, P[u][v], fmaf(wb, P[u][v + 1],
                          fmaf(wc, P[u + 1][v], fmaf(wd, P[u + 1][v + 1], bb))));
                a = leaky(a);
                mx = fmaxf(mx, a);
            }
            p1[c][pp][qq] = mx;
        }
    }

    if (valid) {
        float* xrow = xbuf + (size_t)(r * BS + b) * XDIM + (size_t)(t * 2) * 3481
                      + y * 59 + x;
        #pragma unroll
        for (int c2 = 0; c2 < 2; ++c2) {
            float mx = -3.4e38f;
            #pragma unroll
            for (int a2 = 0; a2 < 2; ++a2)
            #pragma unroll
            for (int b2i = 0; b2i < 2; ++b2i) {
                float acc = b2r[c2];
                #pragma unroll
                for (int c1 = 0; c1 < 2; ++c1)
                #pragma unroll
                for (int du = 0; du < 2; ++du)
                #pragma unroll
                for (int dv = 0; dv < 2; ++dv)
                    acc += w2r[((c2 * 2 + c1) * 2 + du) * 2 + dv]
                         * p1[c1][a2 + du][b2i + dv];
                mx = fmaxf(mx, leaky(acc));
            }
            xrow[(size_t)c2 * 3481] = mx;
        }
    }
}

// ---------------------------------------------------------------------------
// fc1 as tiled split-K GEMM:  psum[kc][row][n] = sum_{k in chunk kc} X[row][k]*W1[n][k]
// Grid: (NKCH, 8 m-tiles). Block 256 thr: tile M=32, N=64(60 used), K=128.
// Thread (ty,tx): m in {2ty,2ty+1}, n in {tx,tx+16,tx+32,tx+48}; float4 over k.
// ---------------------------------------------------------------------------
__global__ __launch_bounds__(256) void gemm_fc1_kernel(
    const float* __restrict__ xbuf, const float* __restrict__ fc1w,
    float* __restrict__ psum)
{
    const int kc   = blockIdx.x;
    const int mt   = blockIdx.y;
    const int tid  = threadIdx.x;
    const int kbase = kc * KC;
    const int rem   = min(KC, XDIM - kbase);   // 7 on last chunk
    const int row0  = mt * 32;

    __shared__ float4 X4[32][33];   // [m][k4], row stride 132 floats
    __shared__ float4 W4[64][33];   // [n][k4]

    float* Xs = reinterpret_cast<float*>(&X4[0][0]);
    float* Ws = reinterpret_cast<float*>(&W4[0][0]);

    for (int idx = tid; idx < 32 * KC; idx += 256) {
        const int m = idx >> 7, k = idx & 127;
        Xs[m * 132 + k] = (k < rem) ? xbuf[(size_t)(row0 + m) * XDIM + kbase + k] : 0.f;
    }
    for (int idx = tid; idx < 64 * KC; idx += 256) {
        const int n = idx >> 7, k = idx & 127;
        Ws[n * 132 + k] = (n < 60 && k < rem) ? fc1w[(size_t)n * XDIM + kbase + k] : 0.f;
    }
    __syncthreads();

    const int ty = tid >> 4, tx = tid & 15;
    const int m0 = ty * 2;

    float acc[2][4];
    #pragma unroll
    for (int i = 0; i < 2; ++i)
    #pragma unroll
    for (int j = 0; j < 4; ++j) acc[i][j] = 0.f;

    #pragma unroll 4
    for (int k4 = 0; k4 < 32; ++k4) {
        const float4 xa = X4[m0][k4];
        const float4 xb = X4[m0 + 1][k4];
        #pragma unroll
        for (int j = 0; j < 4; ++j) {
            const float4 w = W4[tx + 16 * j][k4];
            acc[0][j] += xa.x * w.x + xa.y * w.y + xa.z * w.z + xa.w * w.w;
            acc[1][j] += xb.x * w.x + xb.y * w.y + xb.z * w.z + xb.w * w.w;
        }
    }

    float* po = psum + ((size_t)kc * 256 + row0) * 64;
    #pragma unroll
    for (int i = 0; i < 2; ++i)
    #pragma unroll
    for (int j = 0; j < 4; ++j)
        po[(size_t)(m0 + i) * 64 + tx + 16 * j] = acc[i][j];
}

// ---------------------------------------------------------------------------
// Tail: reduce psum over chunks, bias+leaky, fc2, fc3, * nu, sum over r.
// Grid 128 (one block per b), 64 threads. Deterministic (no atomics).
// ---------------------------------------------------------------------------
__global__ __launch_bounds__(64) void fc_tail_kernel(
    const float* __restrict__ psum,
    const float* __restrict__ fc1b,
    const float* __restrict__ fc2w, const float* __restrict__ fc2b,
    const float* __restrict__ fc3w, const float* __restrict__ fc3b,
    const float* __restrict__ nu, float* __restrict__ out)
{
    const int b = blockIdx.x;
    const int tid = threadIdx.x;

    __shared__ float y1s[64];
    __shared__ float y2s[30];

    float acc_out = 0.f;

    for (int r = 0; r < 2; ++r) {
        const int row = r * 128 + b;
        float s = 0.f;
        #pragma unroll 8
        for (int kcc = 0; kcc < NKCH; ++kcc)
            s += psum[((size_t)kcc * 256 + row) * 64 + tid];
        if (tid < 60) s = leaky(s + fc1b[tid]);
        else s = 0.f;
        y1s[tid] = s;
        __syncthreads();

        if (tid < 30) {
            float a2 = fc2b[tid];
            const float* wr = fc2w + tid * 60;
            #pragma unroll
            for (int k = 0; k < 60; ++k) a2 += wr[k] * y1s[k];
            y2s[tid] = leaky(a2);
        }
        __syncthreads();

        if (tid == 0) {
            float a3 = fc3b[0];
            #pragma unroll
            for (int k = 0; k < 30; ++k) a3 += fc3w[k] * y2s[k];
            acc_out += a3 * nu[b * 2 + r];
        }
        __syncthreads();
    }
    if (tid == 0) out[b] = acc_out;
}

extern "C" void kernel_launch(void* const* d_in, const int* in_sizes, int n_in,
                              void* d_out, int out_size, void* d_ws, size_t ws_size,
                              hipStream_t stream)
{
    const float* xyz   = (const float*)d_in[0];
    const float* cn    = (const float*)d_in[1];
    const float* edisp = (const float*)d_in[2];
    const float* ovlp  = (const float*)d_in[3];
    const float* h0    = (const float*)d_in[4];
    const float* egfn1 = (const float*)d_in[5];
    const float* nu    = (const float*)d_in[6];
    const float* We1   = (const float*)d_in[7];
    const float* be1   = (const float*)d_in[8];
    const float* We2   = (const float*)d_in[9];
    const float* be2   = (const float*)d_in[10];
    // d_in[11..15] = Wc1,bc1,Wc2,bc2,coors_scale: dead code (coors_out discarded)
    const float* Wn1   = (const float*)d_in[16];
    const float* bn1   = (const float*)d_in[17];
    const float* Wn2   = (const float*)d_in[18];
    const float* bn2   = (const float*)d_in[19];
    const float* c1w   = (const float*)d_in[20];
    const float* c1b   = (const float*)d_in[21];
    const float* c2w   = (const float*)d_in[22];
    const float* c2b   = (const float*)d_in[23];
    const float* fc1w  = (const float*)d_in[24];
    const float* fc1b  = (const float*)d_in[25];
    const float* fc2w  = (const float*)d_in[26];
    const float* fc2b  = (const float*)d_in[27];
    const float* fc3w  = (const float*)d_in[28];
    const float* fc3b  = (const float*)d_in[29];

    float* xbuf = (float*)d_ws;                         // 256 x 14087 f32 = 14.43 MB
    float* psum = (float*)((char*)d_ws + 14425088);     // 111 x 256 x 64 f32 = 7.27 MB
    float* out  = (float*)d_out;

    hipLaunchKernelGGL(egnn_kernel, dim3(256), dim3(512), 0, stream,
                       xyz, cn, edisp, egfn1, We1, be1, We2, be2,
                       Wn1, bn1, Wn2, bn2, xbuf);
    hipLaunchKernelGGL(conv_kernel, dim3(2 * 2 * BS * 15), dim3(256), 0, stream,
                       ovlp, h0, c1w, c1b, c2w, c2b, xbuf);
    hipLaunchKernelGGL(gemm_fc1_kernel, dim3(NKCH, 8), dim3(256), 0, stream,
                       xbuf, fc1w, psum);
    hipLaunchKernelGGL(fc_tail_kernel, dim3(128), dim3(64), 0, stream,
                       psum, fc1b, fc2w, fc2b, fc3w, fc3b, nu, out);
}

// Round 3
// 274.614 us; speedup vs baseline: 2.2613x; 1.1276x over previous
//
#include <hip/hip_runtime.h>
#include <hip/hip_bf16.h>

#define XDIM 14087   // 4*3481 conv + 162 atm + 1 egfn1
#define NATM 81
#define BS   128
#define KC   128          // K-chunk for fc1 GEMM
#define NKCH 111          // ceil(14087/128)

__device__ __forceinline__ float fast_rcp(float x) {
    return __builtin_amdgcn_rcpf(x);
}
__device__ __forceinline__ float silu(float z) {
    return z * fast_rcp(1.f + __expf(-z));
}
__device__ __forceinline__ float leaky(float z) {
    return (z > 0.f) ? z : 0.01f * z;
}

// ---------------------------------------------------------------------------
// EGNN: one block per (r,b). 486 active threads = 81 i-nodes x 3 j-parts x 2 k2-halves.
// Writes atm (cols 13924..14085) and egfn1 (col 14086) of xbuf row.
// ---------------------------------------------------------------------------
__global__ __launch_bounds__(512) void egnn_kernel(
    const float* __restrict__ xyz, const float* __restrict__ cn,
    const float* __restrict__ edisp, const float* __restrict__ egfn1,
    const float* __restrict__ We1, const float* __restrict__ be1,
    const float* __restrict__ We2, const float* __restrict__ be2,
    const float* __restrict__ Wn1, const float* __restrict__ bn1,
    const float* __restrict__ Wn2, const float* __restrict__ bn2,
    float* __restrict__ xbuf)
{
    const int bid = blockIdx.x;      // r*128 + b
    const int tid = threadIdx.x;

    __shared__ float sc[NATM][3];
    __shared__ float sf[NATM][2];
    __shared__ float sai[NATM][10];
    __shared__ float sbj[NATM][10];
    __shared__ float sW2[160];
    __shared__ float sbe2[16];
    __shared__ float sw5[10];
    __shared__ float sWn1[72];
    __shared__ float sbn1[4];
    __shared__ float sWn2[8];
    __shared__ float sbn2[2];
    __shared__ float smp[3][NATM][17];   // padded stride 17 to break bank conflicts

    const float* xb = xyz + (size_t)bid * NATM * 3;
    for (int idx = tid; idx < NATM * 3; idx += 512) sc[idx / 3][idx % 3] = xb[idx];
    if (tid < NATM) {
        const float f0 = cn[(size_t)bid * NATM + tid];
        const float f1 = edisp[(size_t)bid * NATM + tid];
        sf[tid][0] = f0; sf[tid][1] = f1;
        #pragma unroll
        for (int k = 0; k < 10; ++k) {
            sai[tid][k] = be1[k] + We1[k * 5 + 0] * f0 + We1[k * 5 + 1] * f1;
            sbj[tid][k] =          We1[k * 5 + 2] * f0 + We1[k * 5 + 3] * f1;
        }
    }
    if (tid < 160) sW2[tid] = We2[tid];
    if (tid < 16)  sbe2[tid] = be2[tid];
    if (tid < 10)  sw5[tid] = We1[tid * 5 + 4];
    if (tid < 72)  sWn1[tid] = Wn1[tid];
    if (tid < 4)   sbn1[tid] = bn1[tid];
    if (tid < 8)   sWn2[tid] = Wn2[tid];
    if (tid < 2)   sbn2[tid] = bn2[tid];
    __syncthreads();

    if (tid < 486) {
        const int i    = tid % 81;
        const int part = (tid / 81) % 3;
        const int half = tid / 243;      // 0 or 1: which 8 of the 16 m-channels

        float W2r[80];
        #pragma unroll
        for (int q = 0; q < 80; ++q) W2r[q] = sW2[half * 80 + q];
        float be2r[8];
        #pragma unroll
        for (int q = 0; q < 8; ++q) be2r[q] = sbe2[half * 8 + q];
        float w5r[10];
        #pragma unroll
        for (int k = 0; k < 10; ++k) w5r[k] = sw5[k];
        float air[10];
        #pragma unroll
        for (int k = 0; k < 10; ++k) air[k] = sai[i][k];
        const float ci0 = sc[i][0], ci1 = sc[i][1], ci2 = sc[i][2];

        float macc[8];
        #pragma unroll
        for (int q = 0; q < 8; ++q) macc[q] = 0.f;

        const int j0 = part * 27;
        for (int j = j0; j < j0 + 27; ++j) {
            const float dx = ci0 - sc[j][0];
            const float dy = ci1 - sc[j][1];
            const float dz = ci2 - sc[j][2];
            const float rd = dx * dx + dy * dy + dz * dz;
            float h[10];
            #pragma unroll
            for (int k = 0; k < 10; ++k) {
                const float z = air[k] + sbj[j][k] + w5r[k] * rd;
                h[k] = silu(z);
            }
            #pragma unroll
            for (int q = 0; q < 8; ++q) {
                float z = be2r[q];
                #pragma unroll
                for (int k = 0; k < 10; ++k) z += W2r[q * 10 + k] * h[k];
                macc[q] += silu(z);
            }
        }
        #pragma unroll
        for (int q = 0; q < 8; ++q) smp[part][i][half * 8 + q] = macc[q];
    }
    __syncthreads();

    if (tid < NATM) {
        float mi[16];
        #pragma unroll
        for (int q = 0; q < 16; ++q)
            mi[q] = smp[0][tid][q] + smp[1][tid][q] + smp[2][tid][q];
        const float f0 = sf[tid][0], f1 = sf[tid][1];
        float n1[4];
        #pragma unroll
        for (int k = 0; k < 4; ++k) {
            float z = sbn1[k] + sWn1[k * 18 + 0] * f0 + sWn1[k * 18 + 1] * f1;
            #pragma unroll
            for (int q = 0; q < 16; ++q) z += sWn1[k * 18 + 2 + q] * mi[q];
            n1[k] = silu(z);
        }
        float* xrow = xbuf + (size_t)bid * XDIM + 13924 + tid * 2;
        #pragma unroll
        for (int c = 0; c < 2; ++c) {
            float z = sbn2[c] + (c ? f1 : f0);
            #pragma unroll
            for (int k = 0; k < 4; ++k) z += sWn2[c * 4 + k] * n1[k];
            xrow[c] = z;
        }
    }
    if (tid == 0) xbuf[(size_t)bid * XDIM + 14086] = egfn1[bid];
}

// ---------------------------------------------------------------------------
// Fused conv1(2x2)+leaky+pool2 + conv2(2x2)+leaky+pool2. No LDS: each thread
// reads its 7x8 input patch directly (coalesced float4; L1 covers overlap).
// ---------------------------------------------------------------------------
__global__ __launch_bounds__(256) void conv_kernel(
    const float* __restrict__ ovlp, const float* __restrict__ h0,
    const float* __restrict__ w1, const float* __restrict__ b1,
    const float* __restrict__ w2, const float* __restrict__ b2,
    float* __restrict__ xbuf)
{
    const int bid   = blockIdx.x;
    const int strip = bid % 15;          // 15 strips x 4 rows = 60 >= 59
    const int img   = bid / 15;          // r*256 + t*128 + b
    const int b     = img & 127;
    const int t     = (img >> 7) & 1;
    const int r     = img >> 8;
    const int tid   = threadIdx.x;

    const int wv = tid >> 6;             // wave -> output row within strip
    const int l  = tid & 63;             // lane -> output col
    const int y  = strip * 4 + wv;
    const int x  = l;
    if (x >= 59 || y >= 59) return;      // no barriers below; early exit ok

    const float4* src4 = reinterpret_cast<const float4*>(
        (t ? h0 : ovlp) + (size_t)(r * BS + b) * 57600);

    float w1r[8], w2r[16], b1r[2], b2r[2];
    #pragma unroll
    for (int k = 0; k < 8; ++k) w1r[k] = w1[k];
    #pragma unroll
    for (int k = 0; k < 16; ++k) w2r[k] = w2[k];
    b1r[0] = b1[0]; b1r[1] = b1[1];
    b2r[0] = b2[0]; b2r[1] = b2[1];

    // 7x8 input patch: rows 4y..4y+6, cols 4x..4x+7 (two float4 per row)
    float P[7][8];
    const int base = 4 * y * 60 + x;     // float4 index
    #pragma unroll
    for (int rr = 0; rr < 7; ++rr) {
        const float4 a  = src4[base + rr * 60];
        const float4 bq = src4[base + rr * 60 + 1];
        P[rr][0] = a.x;  P[rr][1] = a.y;  P[rr][2] = a.z;  P[rr][3] = a.w;
        P[rr][4] = bq.x; P[rr][5] = bq.y; P[rr][6] = bq.z; P[rr][7] = bq.w;
    }

    // conv1 + leaky + pool2 -> p1[2][3][3]
    float p1[2][3][3];
    #pragma unroll
    for (int c = 0; c < 2; ++c) {
        const float wa = w1r[c * 4 + 0], wb = w1r[c * 4 + 1];
        const float wc = w1r[c * 4 + 2], wd = w1r[c * 4 + 3];
        const float bb = b1r[c];
        #pragma unroll
        for (int pp = 0; pp < 3; ++pp)
        #pragma unroll
        for (int qq = 0; qq < 3; ++qq) {
            float mx = -3.4e38f;
            #pragma unroll
            for (int s = 0; s < 2; ++s)
            #pragma unroll
            for (int tt = 0; tt < 2; ++tt) {
                const int u = 2 * pp + s, v = 2 * qq + tt;
                float a = fmaf(wa, P[u][v], fmaf(wb, P[u][v + 1],
                          fmaf(wc, P[u + 1][v], fmaf(wd, P[u + 1][v + 1], bb))));
                a = leaky(a);
                mx = fmaxf(mx, a);
            }
            p1[c][pp][qq] = mx;
        }
    }

    // conv2 + leaky + pool2 -> 2 outputs
    float* xrow = xbuf + (size_t)(r * BS + b) * XDIM + (size_t)(t * 2) * 3481
                  + y * 59 + x;
    #pragma unroll
    for (int c2 = 0; c2 < 2; ++c2) {
        float mx = -3.4e38f;
        #pragma unroll
        for (int a2 = 0; a2 < 2; ++a2)
        #pragma unroll
        for (int b2i = 0; b2i < 2; ++b2i) {
            float acc = b2r[c2];
            #pragma unroll
            for (int c1 = 0; c1 < 2; ++c1)
            #pragma unroll
            for (int du = 0; du < 2; ++du)
            #pragma unroll
            for (int dv = 0; dv < 2; ++dv)
                acc += w2r[((c2 * 2 + c1) * 2 + du) * 2 + dv]
                     * p1[c1][a2 + du][b2i + dv];
            mx = fmaxf(mx, leaky(acc));
        }
        xrow[(size_t)c2 * 3481] = mx;
    }
}

// ---------------------------------------------------------------------------
// fc1 as tiled split-K GEMM:  psum[kc][row][n] = sum_{k in chunk kc} X[row][k]*W1[n][k]
// Grid: (NKCH, 8 m-tiles). Block 256 thr: tile M=32, N=64(60 used), K=128.
// ---------------------------------------------------------------------------
__global__ __launch_bounds__(256) void gemm_fc1_kernel(
    const float* __restrict__ xbuf, const float* __restrict__ fc1w,
    float* __restrict__ psum)
{
    const int kc   = blockIdx.x;
    const int mt   = blockIdx.y;
    const int tid  = threadIdx.x;
    const int kbase = kc * KC;
    const int rem   = min(KC, XDIM - kbase);   // 7 on last chunk
    const int row0  = mt * 32;

    __shared__ float4 X4[32][33];   // [m][k4], row stride 132 floats (2-way banks: free)
    __shared__ float4 W4[64][33];   // [n][k4]

    float* Xs = reinterpret_cast<float*>(&X4[0][0]);
    float* Ws = reinterpret_cast<float*>(&W4[0][0]);

    for (int idx = tid; idx < 32 * KC; idx += 256) {
        const int m = idx >> 7, k = idx & 127;
        Xs[m * 132 + k] = (k < rem) ? xbuf[(size_t)(row0 + m) * XDIM + kbase + k] : 0.f;
    }
    for (int idx = tid; idx < 64 * KC; idx += 256) {
        const int n = idx >> 7, k = idx & 127;
        Ws[n * 132 + k] = (n < 60 && k < rem) ? fc1w[(size_t)n * XDIM + kbase + k] : 0.f;
    }
    __syncthreads();

    const int ty = tid >> 4, tx = tid & 15;
    const int m0 = ty * 2;

    float acc[2][4];
    #pragma unroll
    for (int i = 0; i < 2; ++i)
    #pragma unroll
    for (int j = 0; j < 4; ++j) acc[i][j] = 0.f;

    #pragma unroll 4
    for (int k4 = 0; k4 < 32; ++k4) {
        const float4 xa = X4[m0][k4];
        const float4 xb = X4[m0 + 1][k4];
        #pragma unroll
        for (int j = 0; j < 4; ++j) {
            const float4 w = W4[tx + 16 * j][k4];
            acc[0][j] += xa.x * w.x + xa.y * w.y + xa.z * w.z + xa.w * w.w;
            acc[1][j] += xb.x * w.x + xb.y * w.y + xb.z * w.z + xb.w * w.w;
        }
    }

    float* po = psum + ((size_t)kc * 256 + row0) * 64;
    #pragma unroll
    for (int i = 0; i < 2; ++i)
    #pragma unroll
    for (int j = 0; j < 4; ++j)
        po[(size_t)(m0 + i) * 64 + tx + 16 * j] = acc[i][j];
}

// ---------------------------------------------------------------------------
// Tail: reduce psum over chunks, bias+leaky, fc2, fc3, * nu, sum over r.
// Grid 128 (one block per b), 128 threads (wave 0 -> r=0, wave 1 -> r=1).
// Deterministic (no atomics).
// ---------------------------------------------------------------------------
__global__ __launch_bounds__(128) void fc_tail_kernel(
    const float* __restrict__ psum,
    const float* __restrict__ fc1b,
    const float* __restrict__ fc2w, const float* __restrict__ fc2b,
    const float* __restrict__ fc3w, const float* __restrict__ fc3b,
    const float* __restrict__ nu, float* __restrict__ out)
{
    const int b = blockIdx.x;
    const int tid = threadIdx.x;
    const int rh = tid >> 6;        // which r
    const int n  = tid & 63;

    __shared__ float y1s[2][64];
    __shared__ float y2s[2][30];

    const int row = rh * 128 + b;
    float s = 0.f;
    #pragma unroll 8
    for (int kcc = 0; kcc < NKCH; ++kcc)
        s += psum[((size_t)kcc * 256 + row) * 64 + n];
    y1s[rh][n] = (n < 60) ? leaky(s + fc1b[n]) : 0.f;
    __syncthreads();

    if (n < 30) {
        float a2 = fc2b[n];
        const float* wr = fc2w + n * 60;
        #pragma unroll
        for (int k = 0; k < 60; ++k) a2 += wr[k] * y1s[rh][k];
        y2s[rh][n] = leaky(a2);
    }
    __syncthreads();

    if (tid == 0) {
        float acc_out = 0.f;
        #pragma unroll
        for (int r = 0; r < 2; ++r) {
            float a3 = fc3b[0];
            #pragma unroll
            for (int k = 0; k < 30; ++k) a3 += fc3w[k] * y2s[r][k];
            acc_out += a3 * nu[b * 2 + r];
        }
        out[b] = acc_out;
    }
}

extern "C" void kernel_launch(void* const* d_in, const int* in_sizes, int n_in,
                              void* d_out, int out_size, void* d_ws, size_t ws_size,
                              hipStream_t stream)
{
    const float* xyz   = (const float*)d_in[0];
    const float* cn    = (const float*)d_in[1];
    const float* edisp = (const float*)d_in[2];
    const float* ovlp  = (const float*)d_in[3];
    const float* h0    = (const float*)d_in[4];
    const float* egfn1 = (const float*)d_in[5];
    const float* nu    = (const float*)d_in[6];
    const float* We1   = (const float*)d_in[7];
    const float* be1   = (const float*)d_in[8];
    const float* We2   = (const float*)d_in[9];
    const float* be2   = (const float*)d_in[10];
    // d_in[11..15] = Wc1,bc1,Wc2,bc2,coors_scale: dead code (coors_out discarded)
    const float* Wn1   = (const float*)d_in[16];
    const float* bn1   = (const float*)d_in[17];
    const float* Wn2   = (const float*)d_in[18];
    const float* bn2   = (const float*)d_in[19];
    const float* c1w   = (const float*)d_in[20];
    const float* c1b   = (const float*)d_in[21];
    const float* c2w   = (const float*)d_in[22];
    const float* c2b   = (const float*)d_in[23];
    const float* fc1w  = (const float*)d_in[24];
    const float* fc1b  = (const float*)d_in[25];
    const float* fc2w  = (const float*)d_in[26];
    const float* fc2b  = (const float*)d_in[27];
    const float* fc3w  = (const float*)d_in[28];
    const float* fc3b  = (const float*)d_in[29];

    float* xbuf = (float*)d_ws;                         // 256 x 14087 f32 = 14.43 MB
    float* psum = (float*)((char*)d_ws + 14425088);     // 111 x 256 x 64 f32 = 7.27 MB
    float* out  = (float*)d_out;

    hipLaunchKernelGGL(egnn_kernel, dim3(256), dim3(512), 0, stream,
                       xyz, cn, edisp, egfn1, We1, be1, We2, be2,
                       Wn1, bn1, Wn2, bn2, xbuf);
    hipLaunchKernelGGL(conv_kernel, dim3(2 * 2 * BS * 15), dim3(256), 0, stream,
                       ovlp, h0, c1w, c1b, c2w, c2b, xbuf);
    hipLaunchKernelGGL(gemm_fc1_kernel, dim3(NKCH, 8), dim3(256), 0, stream,
                       xbuf, fc1w, psum);
    hipLaunchKernelGGL(fc_tail_kernel, dim3(128), dim3(128), 0, stream,
                       psum, fc1b, fc2w, fc2b, fc3w, fc3b, nu, out);
}